// Round 2
// baseline (79.293 us; speedup 1.0000x reference)
//
#include <hip/hip_runtime.h>
#include <float.h>

// Problem constants (from reference)
#define BB  8
#define PP  16
#define LL  256     // events per path
#define MM  16      // models
#define LE  2048    // query times per path
#define NQ  (BB * PP * LE)   // 262144 queries total

#define THREADS 256

// ---------------------------------------------------------------------------
// Kernel 1: per-query binary search. One block per (bp, tile-of-512).
// Writes ci (int32) and dt (float) to workspace, coalesced.
// ---------------------------------------------------------------------------
__global__ __launch_bounds__(THREADS) void k_search(
    const float* __restrict__ qt,    // [B,P,LE]
    const float* __restrict__ ev,    // [B,P,LL] sorted
    int*   __restrict__ ci_out,      // [B*P*LE]
    float* __restrict__ dt_out)      // [B*P*LE]
{
    __shared__ float ev_s[LL + 1];
    const int bp   = blockIdx.x >> 2;      // 0..127
    const int tile = blockIdx.x & 3;       // 0..3, 512 queries each
    const int t = threadIdx.x;

    ev_s[t] = ev[bp * LL + t];             // THREADS == LL
    if (t == 0) ev_s[LL] = FLT_MAX;
    __syncthreads();

    const int base = bp * LE + tile * 512;
    #pragma unroll
    for (int k = 0; k < 512; k += THREADS) {
        const int idx = base + k + t;
        const float q = qt[idx];
        // count events strictly < q; sentinel makes fixed 9 steps safe
        int lo = 0, hi = LL;
        #pragma unroll
        for (int s = 0; s < 9; ++s) {
            const int mid = (lo + hi) >> 1;
            if (ev_s[mid] < q) lo = mid + 1; else hi = mid;
        }
        const int cnt = lo;
        const int ci  = (cnt > 0) ? (cnt - 1) : 0;
        const float t_last = (cnt > 0) ? ev_s[ci] : 0.0f;
        ci_out[idx] = ci;
        dt_out[idx] = q - t_last;
    }
}

// ---------------------------------------------------------------------------
// Kernel 2: evaluate intensity. Grid = 128 bp x 4 model-groups x 2 le-tiles
// = 1024 blocks. LDS: 4 models' params packed float4{mu,alpha,beta,0} = 16 KB
// -> 4 blocks/CU. Each thread: 4 consecutive queries, float4 stores.
// ---------------------------------------------------------------------------
#define MG   4                 // models per block
#define QT2  1024              // queries per block (4 per thread)

__global__ __launch_bounds__(THREADS) void k_eval(
    const float* __restrict__ mu,     // [B,M,P,LL]
    const float* __restrict__ alpha,
    const float* __restrict__ beta,
    const int*   __restrict__ ci_in,  // [B*P*LE]
    const float* __restrict__ dt_in,  // [B*P*LE]
    float* __restrict__ out)          // [B,M,P,LE]
{
    __shared__ float4 pr[MG * LL];    // 16 KB: pr[m*LL + l] = {mu, alpha, beta, 0}

    const int mg   =  blockIdx.x & 3;             // model group 0..3
    const int tile = (blockIdx.x >> 2) & 1;       // 0..1
    const int bp   =  blockIdx.x >> 3;            // 0..127
    const int b = bp / PP;
    const int p = bp % PP;
    const int t = threadIdx.x;

    // ---- stage 4 models' params: 4 x 64 float4 per array = 256 iters ----
    {
        const float4* mu4 = (const float4*)mu;
        const float4* al4 = (const float4*)alpha;
        const float4* be4 = (const float4*)beta;
        const int i  = t;                  // exactly one pass: 256 threads
        const int m  = i >> 6;             // 0..3
        const int l4 = i & 63;             // float4 index within row
        const int g  = ((b * MM + mg * MG + m) * PP + p) * (LL / 4) + l4;
        const float4 mv = mu4[g];
        const float4 av = al4[g];
        const float4 bv = be4[g];
        const int o = m * LL + l4 * 4;
        pr[o + 0] = make_float4(mv.x, av.x, bv.x, 0.0f);
        pr[o + 1] = make_float4(mv.y, av.y, bv.y, 0.0f);
        pr[o + 2] = make_float4(mv.z, av.z, bv.z, 0.0f);
        pr[o + 3] = make_float4(mv.w, av.w, bv.w, 0.0f);
    }
    __syncthreads();

    const int q0  = tile * QT2 + 4 * t;           // first of 4 queries
    const int idx = bp * LE + q0;
    const int4   ci4 = *(const int4*)  (ci_in + idx);
    const float4 dt4 = *(const float4*)(dt_in + idx);
    const int ci[4] = {ci4.x, ci4.y, ci4.z, ci4.w};
    const float dt[4] = {dt4.x, dt4.y, dt4.z, dt4.w};

    #pragma unroll
    for (int m = 0; m < MG; ++m) {
        float r[4];
        #pragma unroll
        for (int j = 0; j < 4; ++j) {
            const float4 pm = pr[m * LL + ci[j]];     // one ds_read_b128
            const float e = __expf(-pm.z * dt[j]);
            const float v = pm.x + (pm.y - pm.x) * e; // in [0,1)
            r[j] = __logf(1.0f + __expf(v));          // softplus
        }
        float4* dst = (float4*)(out + ((size_t)(b * MM + mg * MG + m) * PP + p) * LE + q0);
        *dst = make_float4(r[0], r[1], r[2], r[3]);
    }
}

extern "C" void kernel_launch(void* const* d_in, const int* in_sizes, int n_in,
                              void* d_out, int out_size, void* d_ws, size_t ws_size,
                              hipStream_t stream) {
    const float* qt    = (const float*)d_in[0];  // [B,P,LE]
    const float* ev    = (const float*)d_in[1];  // [B,P,LL]
    const float* mu    = (const float*)d_in[2];  // [B,M,P,LL]
    const float* alpha = (const float*)d_in[3];
    const float* beta  = (const float*)d_in[4];
    float* out = (float*)d_out;                  // [B,M,P,LE] fp32

    int*   ci_ws = (int*)d_ws;                   // NQ int32 = 1 MB
    float* dt_ws = (float*)((char*)d_ws + (size_t)NQ * sizeof(int));

    k_search<<<(BB * PP) * 4, THREADS, 0, stream>>>(qt, ev, ci_ws, dt_ws);
    k_eval<<<(BB * PP) * (MM / MG) * (LE / QT2), THREADS, 0, stream>>>(
        mu, alpha, beta, ci_ws, dt_ws, out);
}

// Round 3
// 77.973 us; speedup vs baseline: 1.0169x; 1.0169x over previous
//
#include <hip/hip_runtime.h>
#include <float.h>

// Problem constants (from reference)
#define BB  8
#define PP  16
#define LL  256     // events per path
#define MM  16      // models
#define LE  2048    // query times per path

#define THREADS 256
#define MG   4                 // models per block
#define QT   1024              // queries per block (4 per thread)

// Fused kernel. Grid = 128 bp x 2 le-tiles x 4 model-groups = 1024 blocks.
// LDS: events (1 KB + sentinel) + 4 models' params packed float4{mu,a,b,0}
// (16 KB) -> ~17 KB -> 4+ blocks/CU (grid gives exactly 4/CU).
// Each thread: 4 consecutive queries. Binary searches run with ILP-4 to hide
// the 9-deep dependent LDS chain; eval does one ds_read_b128 per (m,query)
// and one float4 store per (m, 4 queries).
__global__ __launch_bounds__(THREADS) void hawkes_fused(
    const float* __restrict__ qt,     // [B,P,LE]
    const float* __restrict__ ev,     // [B,P,LL] sorted
    const float* __restrict__ mu,     // [B,M,P,LL]
    const float* __restrict__ alpha,
    const float* __restrict__ beta,
    float* __restrict__ out)          // [B,M,P,LE]
{
    __shared__ float  ev_s[LL + 1];
    __shared__ float4 pr[MG * LL];    // 16 KB

    const int mg   =  blockIdx.x & 3;            // model group 0..3
    const int tile = (blockIdx.x >> 2) & 1;      // 0..1
    const int bp   =  blockIdx.x >> 3;           // 0..127
    const int b = bp / PP;
    const int p = bp % PP;
    const int t = threadIdx.x;

    // ---- stage events ----
    ev_s[t] = ev[bp * LL + t];                   // THREADS == LL
    if (t == 0) ev_s[LL] = FLT_MAX;

    // ---- stage 4 models' params, packed ----
    {
        const float4* mu4 = (const float4*)mu;
        const float4* al4 = (const float4*)alpha;
        const float4* be4 = (const float4*)beta;
        const int m  = t >> 6;                   // 0..3
        const int l4 = t & 63;                   // float4 index within row
        const int g  = ((b * MM + mg * MG + m) * PP + p) * (LL / 4) + l4;
        const float4 mv = mu4[g];
        const float4 av = al4[g];
        const float4 bv = be4[g];
        const int o = m * LL + l4 * 4;
        pr[o + 0] = make_float4(mv.x, av.x, bv.x, 0.0f);
        pr[o + 1] = make_float4(mv.y, av.y, bv.y, 0.0f);
        pr[o + 2] = make_float4(mv.z, av.z, bv.z, 0.0f);
        pr[o + 3] = make_float4(mv.w, av.w, bv.w, 0.0f);
    }
    __syncthreads();

    const int q0 = tile * QT + 4 * t;            // first of this thread's 4 queries
    const float4 qv = *(const float4*)(qt + bp * LE + q0);
    const float q[4] = {qv.x, qv.y, qv.z, qv.w};

    // ---- 4 independent branch-free binary searches (ILP-4) ----
    int lo[4] = {0, 0, 0, 0};
    int hi[4] = {LL, LL, LL, LL};
    #pragma unroll
    for (int s = 0; s < 9; ++s) {
        #pragma unroll
        for (int j = 0; j < 4; ++j) {
            const int mid = (lo[j] + hi[j]) >> 1;
            if (ev_s[mid] < q[j]) lo[j] = mid + 1; else hi[j] = mid;
        }
    }
    int   ci[4];
    float dt[4];
    #pragma unroll
    for (int j = 0; j < 4; ++j) {
        const int cnt = lo[j];                   // events strictly before q
        ci[j] = (cnt > 0) ? (cnt - 1) : 0;
        const float t_last = (cnt > 0) ? ev_s[ci[j]] : 0.0f;
        dt[j] = q[j] - t_last;
    }

    // ---- evaluate 4 models x 4 queries ----
    #pragma unroll
    for (int m = 0; m < MG; ++m) {
        float r[4];
        #pragma unroll
        for (int j = 0; j < 4; ++j) {
            const float4 pm = pr[m * LL + ci[j]];     // one ds_read_b128
            const float e = __expf(-pm.z * dt[j]);
            const float v = pm.x + (pm.y - pm.x) * e; // in [0,1)
            r[j] = __logf(1.0f + __expf(v));          // softplus, safe range
        }
        float4* dst = (float4*)(out + ((size_t)(b * MM + mg * MG + m) * PP + p) * LE + q0);
        *dst = make_float4(r[0], r[1], r[2], r[3]);
    }
}

extern "C" void kernel_launch(void* const* d_in, const int* in_sizes, int n_in,
                              void* d_out, int out_size, void* d_ws, size_t ws_size,
                              hipStream_t stream) {
    const float* qt    = (const float*)d_in[0];  // [B,P,LE]
    const float* ev    = (const float*)d_in[1];  // [B,P,LL]
    const float* mu    = (const float*)d_in[2];  // [B,M,P,LL]
    const float* alpha = (const float*)d_in[3];
    const float* beta  = (const float*)d_in[4];
    float* out = (float*)d_out;                  // [B,M,P,LE] fp32

    const int nblocks = (BB * PP) * (LE / QT) * (MM / MG);  // 1024
    hawkes_fused<<<nblocks, THREADS, 0, stream>>>(qt, ev, mu, alpha, beta, out);
}